// Round 2
// baseline (295.768 us; speedup 1.0000x reference)
//
#include <hip/hip_runtime.h>

// ---------------------------------------------------------------------------
// CustomAttention: cosine-sim MHA.  N=1024 seq, B=4 batch, C=1024, H=16, hd=64
//   q/k/v proj (fp16 MFMA) -> l2norm+logit-scale -> flash attention -> out proj
// R1 fix: GEMM LDS staging loop covered only 64 of 128 tile rows (c<512 ->
// c<1024); uninitialized LDS rows fed NaN into the MFMA accumulators.
// ---------------------------------------------------------------------------

typedef _Float16 f16x8 __attribute__((ext_vector_type(8)));
typedef float    f32x4 __attribute__((ext_vector_type(4)));

#define LOG2E 1.4426950408889634f

__device__ __forceinline__ unsigned short f2h(float x) {
    union { _Float16 h; unsigned short u; } cv;
    cv.h = (_Float16)x;
    return cv.u;
}

// ---- fp32 -> fp16 convert (vectorized), n4 = element_count/4 ----
__global__ __launch_bounds__(256) void cvt_kernel(const float* __restrict__ src,
                                                  unsigned short* __restrict__ dst,
                                                  int n4) {
    int i = blockIdx.x * 256 + threadIdx.x;
    if (i < n4) {
        float4 v = ((const float4*)src)[i];
        ushort4 o;
        o.x = f2h(v.x); o.y = f2h(v.y); o.z = f2h(v.z); o.w = f2h(v.w);
        ((ushort4*)dst)[i] = o;
    }
}

// ---- projection GEMM: out = A(4096x1024) @ W^T(1024x1024) + bias ----
// z = 0:q (fp32 scatter to (bh,n,d)), 1:k (same), 2:v (fp16 scatter to vT[bh][d][n])
__global__ __launch_bounds__(256) void proj_gemm(
    const unsigned short* __restrict__ qbf, const unsigned short* __restrict__ kbf,
    const unsigned short* __restrict__ vbf, const unsigned short* __restrict__ wbf,
    const float* __restrict__ bias,
    float* __restrict__ qp, float* __restrict__ kp, unsigned short* __restrict__ vT)
{
    __shared__ __align__(16) unsigned short Asm[128][72];
    __shared__ __align__(16) unsigned short Bsm[128][72];
    int tid = threadIdx.x;
    int lane = tid & 63, wave = tid >> 6;
    int lr = lane & 15, lq = lane >> 4;
    int wr = wave >> 1, wc = wave & 1;
    int z = blockIdx.z;
    const unsigned short* A = (z == 0) ? qbf : (z == 1) ? kbf : vbf;
    const unsigned short* W = wbf + (size_t)z * 1024 * 1024;
    int m0 = blockIdx.y * 128, n0 = blockIdx.x * 128;

    f32x4 acc[4][4];
    for (int i = 0; i < 4; i++) for (int j = 0; j < 4; j++) acc[i][j] = (f32x4){0.f, 0.f, 0.f, 0.f};

    for (int ki = 0; ki < 16; ++ki) {
        for (int c = tid; c < 1024; c += 256) {          // 128 rows x 8 x 16B
            int row = c >> 3, off = (c & 7) << 3;
            *(uint4*)&Asm[row][off] = *(const uint4*)(A + (size_t)(m0 + row) * 1024 + ki * 64 + off);
            *(uint4*)&Bsm[row][off] = *(const uint4*)(W + (size_t)(n0 + row) * 1024 + ki * 64 + off);
        }
        __syncthreads();
        for (int kc = 0; kc < 2; ++kc) {
            f16x8 af[4], bfr[4];
            for (int mi = 0; mi < 4; ++mi) af[mi]  = *(const f16x8*)&Asm[wr * 64 + mi * 16 + lr][kc * 32 + lq * 8];
            for (int ni = 0; ni < 4; ++ni) bfr[ni] = *(const f16x8*)&Bsm[wc * 64 + ni * 16 + lr][kc * 32 + lq * 8];
            for (int mi = 0; mi < 4; ++mi)
                for (int ni = 0; ni < 4; ++ni)
                    acc[mi][ni] = __builtin_amdgcn_mfma_f32_16x16x32_f16(af[mi], bfr[ni], acc[mi][ni], 0, 0, 0);
        }
        __syncthreads();
    }
    for (int mi = 0; mi < 4; ++mi)
        for (int ni = 0; ni < 4; ++ni)
            for (int r = 0; r < 4; ++r) {
                int row = m0 + wr * 64 + mi * 16 + lq * 4 + r;   // m = n*4 + b
                int col = n0 + wc * 64 + ni * 16 + lr;           // c = h*64 + d
                float v = acc[mi][ni][r] + bias[z * 1024 + col];
                int n = row >> 2, b = row & 3;
                int h = col >> 6, d = col & 63;
                int bh = b * 16 + h;
                if (z == 0)      qp[bh * 65536 + n * 64 + d] = v;
                else if (z == 1) kp[bh * 65536 + n * 64 + d] = v;
                else             vT[bh * 65536 + d * 1024 + n] = f2h(v);
            }
}

// ---- l2-normalize rows of 64; fold exp(min(ls,log100))*log2e into q ----
__global__ __launch_bounds__(256) void norm_kernel(
    const float* __restrict__ qp, const float* __restrict__ kp,
    const float* __restrict__ logit_scale,
    unsigned short* __restrict__ qn, unsigned short* __restrict__ kn)
{
    int tid = threadIdx.x;
    int lane = tid & 63, wave = tid >> 6;
    int gw = blockIdx.x * 4 + wave;          // 0 .. 131071
    int tensor = gw >> 16;                   // 0 = q, 1 = k
    int r = gw & 65535;                      // (bh, n) row id
    const float* src = tensor ? kp : qp;
    float v = src[(size_t)r * 64 + lane];
    float ss = v * v;
    for (int off = 1; off < 64; off <<= 1) ss += __shfl_xor(ss, off);
    float scale = 1.0f / fmaxf(sqrtf(ss), 1e-12f);
    if (tensor == 0) {
        int h = (r >> 10) & 15;
        float ls = __expf(fminf(logit_scale[h], 4.6051702f)); // log(100)
        scale *= ls * LOG2E;                                  // softmax in exp2 domain
    }
    (tensor ? kn : qn)[(size_t)r * 64 + lane] = f2h(v * scale);
}

// ---- flash attention: one block = (head bh, 64 q-rows); 4 waves x 16 rows ----
__global__ __launch_bounds__(256) void flash_kernel(
    const unsigned short* __restrict__ qn, const unsigned short* __restrict__ kn,
    const unsigned short* __restrict__ vT, unsigned short* __restrict__ xb)
{
    __shared__ __align__(16) unsigned short K_lds[64][72];
    __shared__ __align__(16) unsigned short V_lds[64][72];    // [dim][kpos]
    __shared__ __align__(16) unsigned short P_lds[4][16][72]; // wave-private
    int tid = threadIdx.x;
    int lane = tid & 63, wave = tid >> 6;
    int lr = lane & 15, lq = lane >> 4;
    int qt = blockIdx.x, bh = blockIdx.y;
    int q0 = qt * 64 + wave * 16;

    f16x8 qf[2];
    for (int kc = 0; kc < 2; ++kc)
        qf[kc] = *(const f16x8*)(qn + (size_t)bh * 65536 + (size_t)(q0 + lr) * 64 + kc * 32 + lq * 8);

    f32x4 o[4];
    for (int i = 0; i < 4; i++) o[i] = (f32x4){0.f, 0.f, 0.f, 0.f};
    float m_run[4], l_run[4];
    for (int r = 0; r < 4; r++) { m_run[r] = -1e30f; l_run[r] = 0.f; }

    for (int kt = 0; kt < 16; ++kt) {
        for (int c = tid; c < 512; c += 256) {           // 64 rows x 8 x 16B
            int row = c >> 3, off = (c & 7) << 3;
            *(uint4*)&K_lds[row][off] = *(const uint4*)(kn + (size_t)bh * 65536 + (size_t)(kt * 64 + row) * 64 + off);
            *(uint4*)&V_lds[row][off] = *(const uint4*)(vT + (size_t)bh * 65536 + (size_t)row * 1024 + kt * 64 + off);
        }
        __syncthreads();

        // S = Q @ K^T  (16 q-rows x 64 kpos per wave), logits already *ls*log2e
        f32x4 s[4];
        for (int ct = 0; ct < 4; ++ct) {
            f32x4 a = (f32x4){0.f, 0.f, 0.f, 0.f};
            for (int kc = 0; kc < 2; ++kc) {
                f16x8 kf = *(const f16x8*)&K_lds[ct * 16 + lr][kc * 32 + lq * 8];
                a = __builtin_amdgcn_mfma_f32_16x16x32_f16(qf[kc], kf, a, 0, 0, 0);
            }
            s[ct] = a;
        }

        // online softmax (exp2 domain); row r of lane = q-row lq*4+r
        float mnew[4], alpha[4], rsum[4];
        for (int r = 0; r < 4; ++r) {
            float rm = fmaxf(fmaxf(s[0][r], s[1][r]), fmaxf(s[2][r], s[3][r]));
            for (int off = 1; off < 16; off <<= 1) rm = fmaxf(rm, __shfl_xor(rm, off));
            mnew[r] = fmaxf(m_run[r], rm);
            alpha[r] = exp2f(m_run[r] - mnew[r]);
            m_run[r] = mnew[r];
            rsum[r] = 0.f;
        }
        for (int ct = 0; ct < 4; ++ct)
            for (int r = 0; r < 4; ++r) {
                float p = exp2f(s[ct][r] - mnew[r]);
                s[ct][r] = p;
                rsum[r] += p;
            }
        for (int r = 0; r < 4; ++r) {
            for (int off = 1; off < 16; off <<= 1) rsum[r] += __shfl_xor(rsum[r], off);
            l_run[r] = l_run[r] * alpha[r] + rsum[r];
        }
        for (int nt = 0; nt < 4; ++nt)
            for (int r = 0; r < 4; ++r) o[nt][r] *= alpha[r];

        // P: C-layout -> A-layout via wave-private LDS (no barrier needed;
        // DS ops from one wave complete in order)
        for (int ct = 0; ct < 4; ++ct)
            for (int r = 0; r < 4; ++r)
                P_lds[wave][lq * 4 + r][ct * 16 + lr] = f2h(s[ct][r]);

        f16x8 pf[2];
        for (int kc = 0; kc < 2; ++kc)
            pf[kc] = *(const f16x8*)&P_lds[wave][lr][kc * 32 + lq * 8];
        for (int nt = 0; nt < 4; ++nt)
            for (int kc = 0; kc < 2; ++kc) {
                f16x8 vf = *(const f16x8*)&V_lds[nt * 16 + lr][kc * 32 + lq * 8];
                o[nt] = __builtin_amdgcn_mfma_f32_16x16x32_f16(pf[kc], vf, o[nt], 0, 0, 0);
            }
        __syncthreads();
    }

    for (int r = 0; r < 4; ++r) {
        float inv = 1.0f / l_run[r];
        int row = q0 + lq * 4 + r;
        for (int nt = 0; nt < 4; ++nt)
            xb[(size_t)bh * 65536 + (size_t)row * 64 + nt * 16 + lr] = f2h(o[nt][r] * inv);
    }
}

// ---- output GEMM: out(4096x1024) = X @ out_w^T + out_b; X gathered from xb(bh,n,d) ----
__global__ __launch_bounds__(256) void out_gemm(
    const unsigned short* __restrict__ xb, const unsigned short* __restrict__ owbf,
    const float* __restrict__ bias, float* __restrict__ outp)
{
    __shared__ __align__(16) unsigned short Asm[128][72];
    __shared__ __align__(16) unsigned short Bsm[128][72];
    int tid = threadIdx.x;
    int lane = tid & 63, wave = tid >> 6;
    int lr = lane & 15, lq = lane >> 4;
    int wr = wave >> 1, wc = wave & 1;
    int m0 = blockIdx.y * 128, n0 = blockIdx.x * 128;

    f32x4 acc[4][4];
    for (int i = 0; i < 4; i++) for (int j = 0; j < 4; j++) acc[i][j] = (f32x4){0.f, 0.f, 0.f, 0.f};

    for (int ki = 0; ki < 16; ++ki) {   // k-chunk of 64 == head ki
        for (int c = tid; c < 1024; c += 256) {          // 128 rows x 8 x 16B
            int row = c >> 3, off = (c & 7) << 3;
            int grow = m0 + row;
            int b = grow & 3, n = grow >> 2;
            *(uint4*)&Asm[row][off] = *(const uint4*)(xb + (size_t)(b * 16 + ki) * 65536 + (size_t)n * 64 + off);
            *(uint4*)&Bsm[row][off] = *(const uint4*)(owbf + (size_t)(n0 + row) * 1024 + ki * 64 + off);
        }
        __syncthreads();
        for (int kc = 0; kc < 2; ++kc) {
            f16x8 af[4], bfr[4];
            for (int mi = 0; mi < 4; ++mi) af[mi]  = *(const f16x8*)&Asm[wr * 64 + mi * 16 + lr][kc * 32 + lq * 8];
            for (int ni = 0; ni < 4; ++ni) bfr[ni] = *(const f16x8*)&Bsm[wc * 64 + ni * 16 + lr][kc * 32 + lq * 8];
            for (int mi = 0; mi < 4; ++mi)
                for (int ni = 0; ni < 4; ++ni)
                    acc[mi][ni] = __builtin_amdgcn_mfma_f32_16x16x32_f16(af[mi], bfr[ni], acc[mi][ni], 0, 0, 0);
        }
        __syncthreads();
    }
    for (int mi = 0; mi < 4; ++mi)
        for (int ni = 0; ni < 4; ++ni)
            for (int r = 0; r < 4; ++r) {
                int row = m0 + wr * 64 + mi * 16 + lq * 4 + r;
                int col = n0 + wc * 64 + ni * 16 + lr;
                outp[(size_t)row * 1024 + col] = acc[mi][ni][r] + bias[col];
            }
}

extern "C" void kernel_launch(void* const* d_in, const int* in_sizes, int n_in,
                              void* d_out, int out_size, void* d_ws, size_t ws_size,
                              hipStream_t stream) {
    const float* query = (const float*)d_in[0];
    const float* key   = (const float*)d_in[1];
    const float* value = (const float*)d_in[2];
    const float* ipw   = (const float*)d_in[3];
    const float* ipb   = (const float*)d_in[4];
    const float* lsc   = (const float*)d_in[5];
    const float* ow    = (const float*)d_in[6];
    const float* ob    = (const float*)d_in[7];
    float* outp = (float*)d_out;

    char* ws = (char*)d_ws;
    unsigned short* qbf  = (unsigned short*)(ws);               // 8 MB fp16 query
    unsigned short* kbf  = (unsigned short*)(ws + 8388608);     // 8 MB
    unsigned short* vbf  = (unsigned short*)(ws + 16777216);    // 8 MB
    unsigned short* wbf  = (unsigned short*)(ws + 25165824);    // 6 MB in_proj_w
    unsigned short* owbf = (unsigned short*)(ws + 31457280);    // 2 MB out_w
    float*          qp   = (float*)(ws + 33554432);             // 16 MB q proj (bh,n,d)
    float*          kp   = (float*)(ws + 50331648);             // 16 MB
    unsigned short* vT   = (unsigned short*)(ws + 67108864);    // 8 MB v^T (bh,d,n)
    unsigned short* qn   = (unsigned short*)(ws + 75497472);    // 8 MB normalized q
    unsigned short* kn   = (unsigned short*)(ws + 83886080);    // 8 MB
    unsigned short* xbuf = (unsigned short*)(ws + 92274688);    // 8 MB attn out (bh,n,d)

    cvt_kernel<<<4096, 256, 0, stream>>>(query, qbf, 1048576);
    cvt_kernel<<<4096, 256, 0, stream>>>(key,   kbf, 1048576);
    cvt_kernel<<<4096, 256, 0, stream>>>(value, vbf, 1048576);
    cvt_kernel<<<3072, 256, 0, stream>>>(ipw,   wbf, 786432);
    cvt_kernel<<<1024, 256, 0, stream>>>(ow,    owbf, 262144);

    proj_gemm<<<dim3(8, 32, 3), 256, 0, stream>>>(qbf, kbf, vbf, wbf, ipb, qp, kp, vT);
    norm_kernel<<<32768, 256, 0, stream>>>(qp, kp, lsc, qn, kn);
    flash_kernel<<<dim3(16, 64), 256, 0, stream>>>(qn, kn, vT, xbuf);
    out_gemm<<<dim3(8, 32), 256, 0, stream>>>(xbuf, owbf, ob, outp);
}

// Round 3
// 240.911 us; speedup vs baseline: 1.2277x; 1.2277x over previous
//
#include <hip/hip_runtime.h>

// ---------------------------------------------------------------------------
// CustomAttention: cosine-sim MHA.  N=1024 seq, B=4 batch, C=1024, H=16, hd=64
// R2: (a) static-max softmax (cos-sim logits bounded by ls*log2e) -> no online
//     rescale, no per-tile shuffles; (b) compute S^T so each lane owns one
//     q-row, P packed b64 writes, PV as O^T = V^T @ P^T; (c) l2norm fused into
//     proj_gemm epilogue (qp/kp fp32 buffers + norm kernel deleted);
//     (d) all fp32->fp16 converts in one launch.  9 kernels -> 4.
// ---------------------------------------------------------------------------

typedef _Float16 f16x8 __attribute__((ext_vector_type(8)));
typedef float    f32x4 __attribute__((ext_vector_type(4)));

#define LOG2E 1.4426950408889634f
#define LOGMAX 4.6051702f   // log(100)

__device__ __forceinline__ unsigned short f2h(float x) {
    union { _Float16 h; unsigned short u; } cv;
    cv.h = (_Float16)x;
    return cv.u;
}

// ---- fp32 -> fp16 convert, all 5 tensors in one launch ----
__global__ __launch_bounds__(256) void cvt_all(
    const float* __restrict__ q, const float* __restrict__ k,
    const float* __restrict__ v, const float* __restrict__ w,
    const float* __restrict__ ow,
    unsigned short* __restrict__ qbf, unsigned short* __restrict__ kbf,
    unsigned short* __restrict__ vbf, unsigned short* __restrict__ wbf,
    unsigned short* __restrict__ owbf)
{
    int b = blockIdx.x;
    const float* src; unsigned short* dst; int idx;
    if      (b < 4096)  { src = q;  dst = qbf;  idx = b; }
    else if (b < 8192)  { src = k;  dst = kbf;  idx = b - 4096; }
    else if (b < 12288) { src = v;  dst = vbf;  idx = b - 8192; }
    else if (b < 15360) { src = w;  dst = wbf;  idx = b - 12288; }
    else                { src = ow; dst = owbf; idx = b - 15360; }
    int i = idx * 256 + threadIdx.x;
    float4 val = ((const float4*)src)[i];
    ushort4 o;
    o.x = f2h(val.x); o.y = f2h(val.y); o.z = f2h(val.z); o.w = f2h(val.w);
    ((ushort4*)dst)[i] = o;
}

// ---- projection GEMM + fused l2norm epilogue ----
// out = A(4096x1024) @ W^T + bias; rows m = n*4+b, cols c = h*64+d.
// z=0: qn fp16 (normalized, *ls*log2e) ; z=1: kn fp16 (normalized);
// z=2: vT fp16 [bh][d][n] (not normalized).
__global__ __launch_bounds__(256) void proj_gemm(
    const unsigned short* __restrict__ qbf, const unsigned short* __restrict__ kbf,
    const unsigned short* __restrict__ vbf, const unsigned short* __restrict__ wbf,
    const float* __restrict__ bias, const float* __restrict__ lsc,
    unsigned short* __restrict__ qn, unsigned short* __restrict__ kn,
    unsigned short* __restrict__ vT)
{
    __shared__ __align__(16) unsigned short Asm[128][72];
    __shared__ __align__(16) unsigned short Bsm[128][72];
    int tid = threadIdx.x;
    int lane = tid & 63, wave = tid >> 6;
    int lr = lane & 15, lq = lane >> 4;
    int wr = wave >> 1, wc = wave & 1;
    int z = blockIdx.z;
    const unsigned short* A = (z == 0) ? qbf : (z == 1) ? kbf : vbf;
    const unsigned short* W = wbf + (size_t)z * 1024 * 1024;
    int m0 = blockIdx.y * 128, n0 = blockIdx.x * 128;

    f32x4 acc[4][4];
    for (int i = 0; i < 4; i++) for (int j = 0; j < 4; j++) acc[i][j] = (f32x4){0.f, 0.f, 0.f, 0.f};

    for (int ki = 0; ki < 16; ++ki) {
        for (int c = tid; c < 1024; c += 256) {          // 128 rows x 8 x 16B
            int row = c >> 3, off = (c & 7) << 3;
            *(uint4*)&Asm[row][off] = *(const uint4*)(A + (size_t)(m0 + row) * 1024 + ki * 64 + off);
            *(uint4*)&Bsm[row][off] = *(const uint4*)(W + (size_t)(n0 + row) * 1024 + ki * 64 + off);
        }
        __syncthreads();
        for (int kc = 0; kc < 2; ++kc) {
            f16x8 af[4], bfr[4];
            for (int mi = 0; mi < 4; ++mi) af[mi]  = *(const f16x8*)&Asm[wr * 64 + mi * 16 + lr][kc * 32 + lq * 8];
            for (int ni = 0; ni < 4; ++ni) bfr[ni] = *(const f16x8*)&Bsm[wc * 64 + ni * 16 + lr][kc * 32 + lq * 8];
            for (int mi = 0; mi < 4; ++mi)
                for (int ni = 0; ni < 4; ++ni)
                    acc[mi][ni] = __builtin_amdgcn_mfma_f32_16x16x32_f16(af[mi], bfr[ni], acc[mi][ni], 0, 0, 0);
        }
        __syncthreads();
    }

    // epilogue: add bias, then per-row (head) l2 norm across d = ni*16+lr
    int h = (n0 >> 6) + wc;                              // head of this wave's cols
    float bv[4];
    for (int ni = 0; ni < 4; ++ni) bv[ni] = bias[z * 1024 + n0 + wc * 64 + ni * 16 + lr];
    for (int mi = 0; mi < 4; ++mi)
        for (int ni = 0; ni < 4; ++ni)
            for (int r = 0; r < 4; ++r) acc[mi][ni][r] += bv[ni];

    float lsfac = __expf(fminf(lsc[h], LOGMAX)) * LOG2E; // folded into q only

    for (int mi = 0; mi < 4; ++mi)
        for (int r = 0; r < 4; ++r) {
            int row = m0 + wr * 64 + mi * 16 + lq * 4 + r;   // m = n*4 + b
            int n = row >> 2, b = row & 3;
            int bh = b * 16 + h;
            if (z < 2) {
                float ss = 0.f;
                for (int ni = 0; ni < 4; ++ni) ss += acc[mi][ni][r] * acc[mi][ni][r];
                for (int off = 1; off < 16; off <<= 1) ss += __shfl_xor(ss, off);
                float scale = 1.0f / fmaxf(sqrtf(ss), 1e-12f);
                if (z == 0) scale *= lsfac;
                unsigned short* dst = (z == 0) ? qn : kn;
                for (int ni = 0; ni < 4; ++ni)
                    dst[(size_t)bh * 65536 + (size_t)n * 64 + ni * 16 + lr] = f2h(acc[mi][ni][r] * scale);
            } else {
                for (int ni = 0; ni < 4; ++ni)
                    vT[(size_t)bh * 65536 + (size_t)(ni * 16 + lr) * 1024 + n] = f2h(acc[mi][ni][r]);
            }
        }
}

// ---- flash attention, static-max softmax, S^T orientation ----
// block = (qt, bh): 64 q-rows, 4 waves x 16 rows; lane owns q-row lr.
__global__ __launch_bounds__(256) void flash_kernel(
    const unsigned short* __restrict__ qn, const unsigned short* __restrict__ kn,
    const unsigned short* __restrict__ vT, const float* __restrict__ lsc,
    unsigned short* __restrict__ xb)
{
    __shared__ __align__(16) unsigned short K_lds[64][72];
    __shared__ __align__(16) unsigned short V_lds[64][72];    // [d][kpos]
    __shared__ __align__(16) unsigned short P_lds[4][16][72]; // [wave][qrow][kpos]
    int tid = threadIdx.x;
    int lane = tid & 63, wave = tid >> 6;
    int lr = lane & 15, lq = lane >> 4;
    int qt = blockIdx.x, bh = blockIdx.y;
    int q0 = qt * 64 + wave * 16;

    // static softmax offset: s <= ls*log2e (cos<=1); +12 keeps p in fp16-normal
    float off = __expf(fminf(lsc[bh & 15], LOGMAX)) * LOG2E - 12.0f;

    f16x8 qf[2];   // B-frag: Q[qrow=lr][d]
    for (int kc = 0; kc < 2; ++kc)
        qf[kc] = *(const f16x8*)(qn + (size_t)bh * 65536 + (size_t)(q0 + lr) * 64 + kc * 32 + lq * 8);

    f32x4 o[4];    // O^T[d = nt*16 + lq*4 + r][qrow = lr]
    for (int i = 0; i < 4; i++) o[i] = (f32x4){0.f, 0.f, 0.f, 0.f};
    float lsum = 0.f;

    for (int kt = 0; kt < 16; ++kt) {
        for (int c = tid; c < 512; c += 256) {           // 64 rows x 8 x 16B
            int row = c >> 3, off4 = (c & 7) << 3;
            *(uint4*)&K_lds[row][off4] = *(const uint4*)(kn + (size_t)bh * 65536 + (size_t)(kt * 64 + row) * 64 + off4);
            *(uint4*)&V_lds[row][off4] = *(const uint4*)(vT + (size_t)bh * 65536 + (size_t)row * 1024 + kt * 64 + off4);
        }
        __syncthreads();

        // S^T[kpos][qrow]: A = K rows (m=kpos), B = Q rows (n=qrow)
        f32x4 s[4];
        for (int ct = 0; ct < 4; ++ct) {
            f32x4 a = (f32x4){0.f, 0.f, 0.f, 0.f};
            for (int kc = 0; kc < 2; ++kc) {
                f16x8 kf = *(const f16x8*)&K_lds[ct * 16 + lr][kc * 32 + lq * 8];
                a = __builtin_amdgcn_mfma_f32_16x16x32_f16(kf, qf[kc], a, 0, 0, 0);
            }
            s[ct] = a;   // lane: qrow=lr, kpos = ct*16 + lq*4 + r
        }

        // p = exp2(s - off); accumulate l per-lane; pack 4 -> one b64 LDS write
        for (int ct = 0; ct < 4; ++ct) {
            float p0 = exp2f(s[ct][0] - off), p1 = exp2f(s[ct][1] - off);
            float p2 = exp2f(s[ct][2] - off), p3 = exp2f(s[ct][3] - off);
            lsum += (p0 + p1) + (p2 + p3);
            ushort4 pw;
            pw.x = f2h(p0); pw.y = f2h(p1); pw.z = f2h(p2); pw.w = f2h(p3);
            *(ushort4*)&P_lds[wave][lr][ct * 16 + lq * 4] = pw;  // wave-private
        }

        // O^T += V^T @ P^T : A = V^T rows (m=d), B = P^T rows (n=qrow)
        f16x8 pf[2];
        for (int kc = 0; kc < 2; ++kc)
            pf[kc] = *(const f16x8*)&P_lds[wave][lr][kc * 32 + lq * 8];
        for (int nt = 0; nt < 4; ++nt)
            for (int kc = 0; kc < 2; ++kc) {
                f16x8 vf = *(const f16x8*)&V_lds[nt * 16 + lr][kc * 32 + lq * 8];
                o[nt] = __builtin_amdgcn_mfma_f32_16x16x32_f16(vf, pf[kc], o[nt], 0, 0, 0);
            }
        __syncthreads();
    }

    // finish l: sum the 4 lq groups holding disjoint kpos for qrow=lr
    lsum += __shfl_xor(lsum, 16);
    lsum += __shfl_xor(lsum, 32);
    float inv = 1.0f / lsum;

    // write xb[bh][qrow][d], 4 packed halves per nt
    for (int nt = 0; nt < 4; ++nt) {
        ushort4 w;
        w.x = f2h(o[nt][0] * inv); w.y = f2h(o[nt][1] * inv);
        w.z = f2h(o[nt][2] * inv); w.w = f2h(o[nt][3] * inv);
        *(ushort4*)(xb + (size_t)bh * 65536 + (size_t)(q0 + lr) * 64 + nt * 16 + lq * 4) = w;
    }
}

// ---- output GEMM: out(4096x1024) = X @ out_w^T + out_b ----
__global__ __launch_bounds__(256) void out_gemm(
    const unsigned short* __restrict__ xb, const unsigned short* __restrict__ owbf,
    const float* __restrict__ bias, float* __restrict__ outp)
{
    __shared__ __align__(16) unsigned short Asm[128][72];
    __shared__ __align__(16) unsigned short Bsm[128][72];
    int tid = threadIdx.x;
    int lane = tid & 63, wave = tid >> 6;
    int lr = lane & 15, lq = lane >> 4;
    int wr = wave >> 1, wc = wave & 1;
    int m0 = blockIdx.y * 128, n0 = blockIdx.x * 128;

    f32x4 acc[4][4];
    for (int i = 0; i < 4; i++) for (int j = 0; j < 4; j++) acc[i][j] = (f32x4){0.f, 0.f, 0.f, 0.f};

    for (int ki = 0; ki < 16; ++ki) {   // k-chunk of 64 == head ki
        for (int c = tid; c < 1024; c += 256) {
            int row = c >> 3, off = (c & 7) << 3;
            int grow = m0 + row;
            int b = grow & 3, n = grow >> 2;
            *(uint4*)&Asm[row][off] = *(const uint4*)(xb + (size_t)(b * 16 + ki) * 65536 + (size_t)n * 64 + off);
            *(uint4*)&Bsm[row][off] = *(const uint4*)(owbf + (size_t)(n0 + row) * 1024 + ki * 64 + off);
        }
        __syncthreads();
        for (int kc = 0; kc < 2; ++kc) {
            f16x8 af[4], bfr[4];
            for (int mi = 0; mi < 4; ++mi) af[mi]  = *(const f16x8*)&Asm[wr * 64 + mi * 16 + lr][kc * 32 + lq * 8];
            for (int ni = 0; ni < 4; ++ni) bfr[ni] = *(const f16x8*)&Bsm[wc * 64 + ni * 16 + lr][kc * 32 + lq * 8];
            for (int mi = 0; mi < 4; ++mi)
                for (int ni = 0; ni < 4; ++ni)
                    acc[mi][ni] = __builtin_amdgcn_mfma_f32_16x16x32_f16(af[mi], bfr[ni], acc[mi][ni], 0, 0, 0);
        }
        __syncthreads();
    }
    for (int mi = 0; mi < 4; ++mi)
        for (int ni = 0; ni < 4; ++ni)
            for (int r = 0; r < 4; ++r) {
                int row = m0 + wr * 64 + mi * 16 + lq * 4 + r;
                int col = n0 + wc * 64 + ni * 16 + lr;
                outp[(size_t)row * 1024 + col] = acc[mi][ni][r] + bias[col];
            }
}

extern "C" void kernel_launch(void* const* d_in, const int* in_sizes, int n_in,
                              void* d_out, int out_size, void* d_ws, size_t ws_size,
                              hipStream_t stream) {
    const float* query = (const float*)d_in[0];
    const float* key   = (const float*)d_in[1];
    const float* value = (const float*)d_in[2];
    const float* ipw   = (const float*)d_in[3];
    const float* ipb   = (const float*)d_in[4];
    const float* lsc   = (const float*)d_in[5];
    const float* ow    = (const float*)d_in[6];
    const float* ob    = (const float*)d_in[7];
    float* outp = (float*)d_out;

    char* ws = (char*)d_ws;
    unsigned short* qbf  = (unsigned short*)(ws);               // 8 MB fp16 query
    unsigned short* kbf  = (unsigned short*)(ws + 8388608);     // 8 MB
    unsigned short* vbf  = (unsigned short*)(ws + 16777216);    // 8 MB
    unsigned short* wbf  = (unsigned short*)(ws + 25165824);    // 6 MB in_proj_w
    unsigned short* owbf = (unsigned short*)(ws + 31457280);    // 2 MB out_w
    unsigned short* qn   = (unsigned short*)(ws + 33554432);    // 8 MB normalized q (bh,n,d)
    unsigned short* kn   = (unsigned short*)(ws + 41943040);    // 8 MB normalized k
    unsigned short* vT   = (unsigned short*)(ws + 50331648);    // 8 MB v^T (bh,d,n)
    unsigned short* xbuf = (unsigned short*)(ws + 58720256);    // 8 MB attn out (bh,n,d)

    cvt_all<<<16384, 256, 0, stream>>>(query, key, value, ipw, ow,
                                       qbf, kbf, vbf, wbf, owbf);
    proj_gemm<<<dim3(8, 32, 3), 256, 0, stream>>>(qbf, kbf, vbf, wbf, ipb, lsc,
                                                  qn, kn, vT);
    flash_kernel<<<dim3(16, 64), 256, 0, stream>>>(qn, kn, vT, lsc, xbuf);
    out_gemm<<<dim3(8, 32), 256, 0, stream>>>(xbuf, owbf, ob, outp);
}

// Round 4
// 218.420 us; speedup vs baseline: 1.3541x; 1.1030x over previous
//
#include <hip/hip_runtime.h>

// ---------------------------------------------------------------------------
// CustomAttention: cosine-sim MHA.  N=1024 seq, B=4 batch, C=1024, H=16, hd=64
// R3: (a) async global->LDS staging (global_load_lds width=16) in proj/flash/
//     out — removes the VGPR round-trip (m97 ladder step, 1.7x on GEMM);
//     (b) unpadded [rows][64] LDS tiles with XOR chunk swizzle
//     (LDS chunk c holds global chunk c^(row&7)) -> 2-way conflicts only;
//     (c) flash writes attn output directly in (n*4+b, h*64+d) row-major so
//     out_gemm stages it contiguously; (d) out_gemm 128x64 tiles, 512 blocks.
// ---------------------------------------------------------------------------

typedef _Float16 f16x8 __attribute__((ext_vector_type(8)));
typedef float    f32x4 __attribute__((ext_vector_type(4)));

#define LOG2E 1.4426950408889634f
#define LOGMAX 4.6051702f   // log(100)

#define GLOAD16(g, l) \
    __builtin_amdgcn_global_load_lds((__attribute__((address_space(1))) void*)(g), \
                                     (__attribute__((address_space(3))) void*)(l), 16, 0, 0)

__device__ __forceinline__ unsigned short f2h(float x) {
    union { _Float16 h; unsigned short u; } cv;
    cv.h = (_Float16)x;
    return cv.u;
}

// ---- fp32 -> fp16 convert, all 5 tensors in one launch ----
__global__ __launch_bounds__(256) void cvt_all(
    const float* __restrict__ q, const float* __restrict__ k,
    const float* __restrict__ v, const float* __restrict__ w,
    const float* __restrict__ ow,
    unsigned short* __restrict__ qbf, unsigned short* __restrict__ kbf,
    unsigned short* __restrict__ vbf, unsigned short* __restrict__ wbf,
    unsigned short* __restrict__ owbf)
{
    int b = blockIdx.x;
    const float* src; unsigned short* dst; int idx;
    if      (b < 4096)  { src = q;  dst = qbf;  idx = b; }
    else if (b < 8192)  { src = k;  dst = kbf;  idx = b - 4096; }
    else if (b < 12288) { src = v;  dst = vbf;  idx = b - 8192; }
    else if (b < 15360) { src = w;  dst = wbf;  idx = b - 12288; }
    else                { src = ow; dst = owbf; idx = b - 15360; }
    int i = idx * 256 + threadIdx.x;
    float4 val = ((const float4*)src)[i];
    ushort4 o;
    o.x = f2h(val.x); o.y = f2h(val.y); o.z = f2h(val.z); o.w = f2h(val.w);
    ((ushort4*)dst)[i] = o;
}

// ---- projection GEMM + fused l2norm epilogue ----
// out = A(4096x1024) @ W^T + bias; rows m = n*4+b, cols c = h*64+d.
// z=0: qn fp16 (normalized, *ls*log2e); z=1: kn; z=2: vT [bh][d][n].
__global__ __launch_bounds__(256) void proj_gemm(
    const unsigned short* __restrict__ qbf, const unsigned short* __restrict__ kbf,
    const unsigned short* __restrict__ vbf, const unsigned short* __restrict__ wbf,
    const float* __restrict__ bias, const float* __restrict__ lsc,
    unsigned short* __restrict__ qn, unsigned short* __restrict__ kn,
    unsigned short* __restrict__ vT)
{
    __shared__ __align__(16) unsigned short AsmF[128 * 64];
    __shared__ __align__(16) unsigned short BsmF[128 * 64];
    int tid = threadIdx.x;
    int lane = tid & 63, wave = tid >> 6;
    int lr = lane & 15, lq = lane >> 4;
    int wr = wave >> 1, wc = wave & 1;
    int z = blockIdx.z;
    const unsigned short* A = (z == 0) ? qbf : (z == 1) ? kbf : vbf;
    const unsigned short* W = wbf + (size_t)z * 1024 * 1024;
    int m0 = blockIdx.y * 128, n0 = blockIdx.x * 128;

    // async-staging addresses: lane l -> row l>>3, lds chunk l&7,
    // global chunk (l&7)^(l>>3)  (xor swizzle, row&7 == l>>3)
    int rl = lane >> 3;
    int cg = ((lane & 7) ^ rl) << 3;                     // halves
    const unsigned short* gA = A + (size_t)(m0 + wave * 32 + rl) * 1024 + cg;
    const unsigned short* gB = W + (size_t)(n0 + wave * 32 + rl) * 1024 + cg;
    unsigned short* lA = &AsmF[wave * 32 * 64];
    unsigned short* lB = &BsmF[wave * 32 * 64];

    // reader chunk offsets (halves): global chunk kc*4+lq at LDS (kc*4+lq)^(lr&7)
    int swz = lr & 7;
    int c0 = (lq ^ swz) << 3;
    int c1 = ((lq ^ 4) ^ swz) << 3;

    f32x4 acc[4][4];
    for (int i = 0; i < 4; i++) for (int j = 0; j < 4; j++) acc[i][j] = (f32x4){0.f, 0.f, 0.f, 0.f};

    for (int ki = 0; ki < 16; ++ki) {
        for (int j = 0; j < 4; ++j) {                    // 8 rows / instr
            GLOAD16(gA + ki * 64 + j * 8192, lA + j * 512);
            GLOAD16(gB + ki * 64 + j * 8192, lB + j * 512);
        }
        __syncthreads();
        for (int kc = 0; kc < 2; ++kc) {
            int co = kc ? c1 : c0;
            f16x8 af[4], bfr[4];
            for (int mi = 0; mi < 4; ++mi) af[mi]  = *(const f16x8*)&AsmF[(wr * 64 + mi * 16 + lr) * 64 + co];
            for (int ni = 0; ni < 4; ++ni) bfr[ni] = *(const f16x8*)&BsmF[(wc * 64 + ni * 16 + lr) * 64 + co];
            for (int mi = 0; mi < 4; ++mi)
                for (int ni = 0; ni < 4; ++ni)
                    acc[mi][ni] = __builtin_amdgcn_mfma_f32_16x16x32_f16(af[mi], bfr[ni], acc[mi][ni], 0, 0, 0);
        }
        __syncthreads();
    }

    // epilogue: bias, per-(row,head) l2 norm across d = ni*16+lr
    int h = (n0 >> 6) + wc;
    float bv[4];
    for (int ni = 0; ni < 4; ++ni) bv[ni] = bias[z * 1024 + n0 + wc * 64 + ni * 16 + lr];
    for (int mi = 0; mi < 4; ++mi)
        for (int ni = 0; ni < 4; ++ni)
            for (int r = 0; r < 4; ++r) acc[mi][ni][r] += bv[ni];

    float lsfac = __expf(fminf(lsc[h], LOGMAX)) * LOG2E;

    for (int mi = 0; mi < 4; ++mi)
        for (int r = 0; r < 4; ++r) {
            int row = m0 + wr * 64 + mi * 16 + lq * 4 + r;   // m = n*4 + b
            int n = row >> 2, b = row & 3;
            int bh = b * 16 + h;
            if (z < 2) {
                float ss = 0.f;
                for (int ni = 0; ni < 4; ++ni) ss += acc[mi][ni][r] * acc[mi][ni][r];
                for (int off = 1; off < 16; off <<= 1) ss += __shfl_xor(ss, off);
                float scale = 1.0f / fmaxf(sqrtf(ss), 1e-12f);
                if (z == 0) scale *= lsfac;
                unsigned short* dst = (z == 0) ? qn : kn;
                for (int ni = 0; ni < 4; ++ni)
                    dst[(size_t)bh * 65536 + (size_t)n * 64 + ni * 16 + lr] = f2h(acc[mi][ni][r] * scale);
            } else {
                for (int ni = 0; ni < 4; ++ni)
                    vT[(size_t)bh * 65536 + (size_t)(ni * 16 + lr) * 1024 + n] = f2h(acc[mi][ni][r]);
            }
        }
}

// ---- flash attention, static-max softmax, S^T orientation ----
__global__ __launch_bounds__(256) void flash_kernel(
    const unsigned short* __restrict__ qn, const unsigned short* __restrict__ kn,
    const unsigned short* __restrict__ vT, const float* __restrict__ lsc,
    unsigned short* __restrict__ xb)
{
    __shared__ __align__(16) unsigned short K_flat[64 * 64];
    __shared__ __align__(16) unsigned short V_flat[64 * 64];  // [d][kpos]
    __shared__ __align__(16) unsigned short P_lds[4][16][72]; // [wave][qrow][kpos]
    int tid = threadIdx.x;
    int lane = tid & 63, wave = tid >> 6;
    int lr = lane & 15, lq = lane >> 4;
    int qt = blockIdx.x, bh = blockIdx.y;
    int q0 = qt * 64 + wave * 16;

    float off = __expf(fminf(lsc[bh & 15], LOGMAX)) * LOG2E - 12.0f;

    f16x8 qf[2];   // B-frag: Q[qrow=lr][d]
    for (int kc = 0; kc < 2; ++kc)
        qf[kc] = *(const f16x8*)(qn + (size_t)bh * 65536 + (size_t)(q0 + lr) * 64 + kc * 32 + lq * 8);

    // async staging: wave w stages K rows/V dims w*16 .. w*16+15
    int rl = lane >> 3;
    int cg = ((lane & 7) ^ rl) << 3;
    const unsigned short* gK = kn + (size_t)bh * 65536 + (size_t)(wave * 16 + rl) * 64 + cg;
    const unsigned short* gV = vT + (size_t)bh * 65536 + (size_t)(wave * 16 + rl) * 1024 + cg;
    unsigned short* lK = &K_flat[wave * 16 * 64];
    unsigned short* lV = &V_flat[wave * 16 * 64];
    int swz = lr & 7;
    int c0 = (lq ^ swz) << 3;
    int c1 = ((lq ^ 4) ^ swz) << 3;

    f32x4 o[4];    // O^T[d = nt*16 + lq*4 + r][qrow = lr]
    for (int i = 0; i < 4; i++) o[i] = (f32x4){0.f, 0.f, 0.f, 0.f};
    float lsum = 0.f;

    for (int kt = 0; kt < 16; ++kt) {
        for (int j = 0; j < 2; ++j) {
            GLOAD16(gK + kt * 4096 + j * 512,  lK + j * 512);
            GLOAD16(gV + kt * 64  + j * 8192,  lV + j * 512);
        }
        __syncthreads();

        // S^T[kpos][qrow]: A = K rows (m=kpos), B = Q rows (n=qrow)
        f32x4 s[4];
        for (int ct = 0; ct < 4; ++ct) {
            f32x4 a = (f32x4){0.f, 0.f, 0.f, 0.f};
            for (int kc = 0; kc < 2; ++kc) {
                f16x8 kf = *(const f16x8*)&K_flat[(ct * 16 + lr) * 64 + (kc ? c1 : c0)];
                a = __builtin_amdgcn_mfma_f32_16x16x32_f16(kf, qf[kc], a, 0, 0, 0);
            }
            s[ct] = a;   // lane: qrow=lr, kpos = ct*16 + lq*4 + r
        }

        for (int ct = 0; ct < 4; ++ct) {
            float p0 = exp2f(s[ct][0] - off), p1 = exp2f(s[ct][1] - off);
            float p2 = exp2f(s[ct][2] - off), p3 = exp2f(s[ct][3] - off);
            lsum += (p0 + p1) + (p2 + p3);
            ushort4 pw;
            pw.x = f2h(p0); pw.y = f2h(p1); pw.z = f2h(p2); pw.w = f2h(p3);
            *(ushort4*)&P_lds[wave][lr][ct * 16 + lq * 4] = pw;  // wave-private
        }

        // O^T += V^T @ P^T
        f16x8 pf[2];
        for (int kc = 0; kc < 2; ++kc)
            pf[kc] = *(const f16x8*)&P_lds[wave][lr][kc * 32 + lq * 8];
        for (int nt = 0; nt < 4; ++nt)
            for (int kc = 0; kc < 2; ++kc) {
                f16x8 vf = *(const f16x8*)&V_flat[(nt * 16 + lr) * 64 + (kc ? c1 : c0)];
                o[nt] = __builtin_amdgcn_mfma_f32_16x16x32_f16(vf, pf[kc], o[nt], 0, 0, 0);
            }
        __syncthreads();
    }

    lsum += __shfl_xor(lsum, 16);
    lsum += __shfl_xor(lsum, 32);
    float inv = 1.0f / lsum;

    // write xb row-major (m = n*4+b, c = h*64+d) so out_gemm stages contiguously
    int b = bh >> 4, h = bh & 15;
    for (int nt = 0; nt < 4; ++nt) {
        ushort4 w;
        w.x = f2h(o[nt][0] * inv); w.y = f2h(o[nt][1] * inv);
        w.z = f2h(o[nt][2] * inv); w.w = f2h(o[nt][3] * inv);
        size_t m = (size_t)(q0 + lr) * 4 + b;
        *(ushort4*)(xb + m * 1024 + h * 64 + nt * 16 + lq * 4) = w;
    }
}

// ---- output GEMM: out(4096x1024) = X @ out_w^T + out_b;  128x64 tiles ----
__global__ __launch_bounds__(256) void out_gemm(
    const unsigned short* __restrict__ xb, const unsigned short* __restrict__ owbf,
    const float* __restrict__ bias, float* __restrict__ outp)
{
    __shared__ __align__(16) unsigned short AsmF[128 * 64];
    __shared__ __align__(16) unsigned short BsmF[64 * 64];
    int tid = threadIdx.x;
    int lane = tid & 63, wave = tid >> 6;
    int lr = lane & 15, lq = lane >> 4;
    int m0 = blockIdx.y * 128, n0 = blockIdx.x * 64;

    int rl = lane >> 3;
    int cg = ((lane & 7) ^ rl) << 3;
    const unsigned short* gA = xb   + (size_t)(m0 + wave * 32 + rl) * 1024 + cg;
    const unsigned short* gB = owbf + (size_t)(n0 + wave * 16 + rl) * 1024 + cg;
    unsigned short* lA = &AsmF[wave * 32 * 64];
    unsigned short* lB = &BsmF[wave * 16 * 64];
    int swz = lr & 7;
    int c0 = (lq ^ swz) << 3;
    int c1 = ((lq ^ 4) ^ swz) << 3;

    f32x4 acc[2][4];
    for (int i = 0; i < 2; i++) for (int j = 0; j < 4; j++) acc[i][j] = (f32x4){0.f, 0.f, 0.f, 0.f};

    for (int ki = 0; ki < 16; ++ki) {
        for (int j = 0; j < 4; ++j)
            GLOAD16(gA + ki * 64 + j * 8192, lA + j * 512);
        for (int j = 0; j < 2; ++j)
            GLOAD16(gB + ki * 64 + j * 8192, lB + j * 512);
        __syncthreads();
        for (int kc = 0; kc < 2; ++kc) {
            int co = kc ? c1 : c0;
            f16x8 af[2], bfr[4];
            for (int mi = 0; mi < 2; ++mi) af[mi]  = *(const f16x8*)&AsmF[(wave * 32 + mi * 16 + lr) * 64 + co];
            for (int ni = 0; ni < 4; ++ni) bfr[ni] = *(const f16x8*)&BsmF[(ni * 16 + lr) * 64 + co];
            for (int mi = 0; mi < 2; ++mi)
                for (int ni = 0; ni < 4; ++ni)
                    acc[mi][ni] = __builtin_amdgcn_mfma_f32_16x16x32_f16(af[mi], bfr[ni], acc[mi][ni], 0, 0, 0);
        }
        __syncthreads();
    }
    for (int mi = 0; mi < 2; ++mi)
        for (int ni = 0; ni < 4; ++ni)
            for (int r = 0; r < 4; ++r) {
                int row = m0 + wave * 32 + mi * 16 + lq * 4 + r;
                int col = n0 + ni * 16 + lr;
                outp[(size_t)row * 1024 + col] = acc[mi][ni][r] + bias[col];
            }
}

extern "C" void kernel_launch(void* const* d_in, const int* in_sizes, int n_in,
                              void* d_out, int out_size, void* d_ws, size_t ws_size,
                              hipStream_t stream) {
    const float* query = (const float*)d_in[0];
    const float* key   = (const float*)d_in[1];
    const float* value = (const float*)d_in[2];
    const float* ipw   = (const float*)d_in[3];
    const float* ipb   = (const float*)d_in[4];
    const float* lsc   = (const float*)d_in[5];
    const float* ow    = (const float*)d_in[6];
    const float* ob    = (const float*)d_in[7];
    float* outp = (float*)d_out;

    char* ws = (char*)d_ws;
    unsigned short* qbf  = (unsigned short*)(ws);               // 8 MB fp16 query
    unsigned short* kbf  = (unsigned short*)(ws + 8388608);     // 8 MB
    unsigned short* vbf  = (unsigned short*)(ws + 16777216);    // 8 MB
    unsigned short* wbf  = (unsigned short*)(ws + 25165824);    // 6 MB in_proj_w
    unsigned short* owbf = (unsigned short*)(ws + 31457280);    // 2 MB out_w
    unsigned short* qn   = (unsigned short*)(ws + 33554432);    // 8 MB normalized q (bh,n,d)
    unsigned short* kn   = (unsigned short*)(ws + 41943040);    // 8 MB normalized k
    unsigned short* vT   = (unsigned short*)(ws + 50331648);    // 8 MB v^T (bh,d,n)
    unsigned short* xbuf = (unsigned short*)(ws + 58720256);    // 8 MB attn out (m, c) row-major

    cvt_all<<<16384, 256, 0, stream>>>(query, key, value, ipw, ow,
                                       qbf, kbf, vbf, wbf, owbf);
    proj_gemm<<<dim3(8, 32, 3), 256, 0, stream>>>(qbf, kbf, vbf, wbf, ipb, lsc,
                                                  qn, kn, vT);
    flash_kernel<<<dim3(16, 64), 256, 0, stream>>>(qn, kn, vT, lsc, xbuf);
    out_gemm<<<dim3(16, 32), 256, 0, stream>>>(xbuf, owbf, ob, outp);
}

// Round 5
// 212.323 us; speedup vs baseline: 1.3930x; 1.0287x over previous
//
#include <hip/hip_runtime.h>

// ---------------------------------------------------------------------------
// CustomAttention: cosine-sim MHA.  N=1024 seq, B=4 batch, C=1024, H=16, hd=64
// R5: XCD-aware block swizzle (XCD = linear_id % 8) for proj/flash/out.
//     R4's grid put one n-column per XCD -> every XCD fetched ALL of A
//     (FETCH_SIZE 101 MB vs ~30 MB input).  Now each XCD owns a y-stripe
//     (proj/out) or bh-stripe (flash) with x/qt fastest, so the per-XCD L2
//     working set is ~3-9 MB and tiles stay L2-hot.
// ---------------------------------------------------------------------------

typedef _Float16 f16x8 __attribute__((ext_vector_type(8)));
typedef float    f32x4 __attribute__((ext_vector_type(4)));

#define LOG2E 1.4426950408889634f
#define LOGMAX 4.6051702f   // log(100)

#define GLOAD16(g, l) \
    __builtin_amdgcn_global_load_lds((__attribute__((address_space(1))) void*)(g), \
                                     (__attribute__((address_space(3))) void*)(l), 16, 0, 0)

__device__ __forceinline__ unsigned short f2h(float x) {
    union { _Float16 h; unsigned short u; } cv;
    cv.h = (_Float16)x;
    return cv.u;
}

// ---- fp32 -> fp16 convert, all 5 tensors in one launch ----
__global__ __launch_bounds__(256) void cvt_all(
    const float* __restrict__ q, const float* __restrict__ k,
    const float* __restrict__ v, const float* __restrict__ w,
    const float* __restrict__ ow,
    unsigned short* __restrict__ qbf, unsigned short* __restrict__ kbf,
    unsigned short* __restrict__ vbf, unsigned short* __restrict__ wbf,
    unsigned short* __restrict__ owbf)
{
    int b = blockIdx.x;
    const float* src; unsigned short* dst; int idx;
    if      (b < 4096)  { src = q;  dst = qbf;  idx = b; }
    else if (b < 8192)  { src = k;  dst = kbf;  idx = b - 4096; }
    else if (b < 12288) { src = v;  dst = vbf;  idx = b - 8192; }
    else if (b < 15360) { src = w;  dst = wbf;  idx = b - 12288; }
    else                { src = ow; dst = owbf; idx = b - 15360; }
    int i = idx * 256 + threadIdx.x;
    float4 val = ((const float4*)src)[i];
    ushort4 o;
    o.x = f2h(val.x); o.y = f2h(val.y); o.z = f2h(val.z); o.w = f2h(val.w);
    ((ushort4*)dst)[i] = o;
}

// ---- projection GEMM + fused l2norm epilogue ----
// out = A(4096x1024) @ W^T + bias; rows m = n*4+b, cols c = h*64+d.
// z=0: qn fp16 (normalized, *ls*log2e); z=1: kn; z=2: vT [bh][d][n].
// 1D grid of 768; XCD swizzle: each XCD owns 4 m-tiles x all n x all z,
// n-tile fastest (W slice 2 MB stays hot in the XCD's 4 MB L2).
__global__ __launch_bounds__(256) void proj_gemm(
    const unsigned short* __restrict__ qbf, const unsigned short* __restrict__ kbf,
    const unsigned short* __restrict__ vbf, const unsigned short* __restrict__ wbf,
    const float* __restrict__ bias, const float* __restrict__ lsc,
    unsigned short* __restrict__ qn, unsigned short* __restrict__ kn,
    unsigned short* __restrict__ vT)
{
    __shared__ __align__(16) unsigned short AsmF[128 * 64];
    __shared__ __align__(16) unsigned short BsmF[128 * 64];
    int tid = threadIdx.x;
    int lane = tid & 63, wave = tid >> 6;
    int lr = lane & 15, lq = lane >> 4;
    int wr = wave >> 1, wc = wave & 1;

    // XCD-aware decode: lin = z*32*8 + yy*64 + xt*8 + xcd
    int lin = blockIdx.x;
    int xcd = lin & 7, s = lin >> 3;
    int xt = s & 7, yy = (s >> 3) & 3, z = s >> 5;
    int m0 = (xcd * 4 + yy) * 128, n0 = xt * 128;

    const unsigned short* A = (z == 0) ? qbf : (z == 1) ? kbf : vbf;
    const unsigned short* W = wbf + (size_t)z * 1024 * 1024;

    // async staging: lane l -> row l>>3, lds chunk l&7, global chunk (l&7)^(l>>3)
    int rl = lane >> 3;
    int cg = ((lane & 7) ^ rl) << 3;                     // halves
    const unsigned short* gA = A + (size_t)(m0 + wave * 32 + rl) * 1024 + cg;
    const unsigned short* gB = W + (size_t)(n0 + wave * 32 + rl) * 1024 + cg;
    unsigned short* lA = &AsmF[wave * 32 * 64];
    unsigned short* lB = &BsmF[wave * 32 * 64];

    int swz = lr & 7;
    int c0 = (lq ^ swz) << 3;
    int c1 = ((lq ^ 4) ^ swz) << 3;

    f32x4 acc[4][4];
    for (int i = 0; i < 4; i++) for (int j = 0; j < 4; j++) acc[i][j] = (f32x4){0.f, 0.f, 0.f, 0.f};

    for (int ki = 0; ki < 16; ++ki) {
        for (int j = 0; j < 4; ++j) {                    // 8 rows / instr
            GLOAD16(gA + ki * 64 + j * 8192, lA + j * 512);
            GLOAD16(gB + ki * 64 + j * 8192, lB + j * 512);
        }
        __syncthreads();
        for (int kc = 0; kc < 2; ++kc) {
            int co = kc ? c1 : c0;
            f16x8 af[4], bfr[4];
            for (int mi = 0; mi < 4; ++mi) af[mi]  = *(const f16x8*)&AsmF[(wr * 64 + mi * 16 + lr) * 64 + co];
            for (int ni = 0; ni < 4; ++ni) bfr[ni] = *(const f16x8*)&BsmF[(wc * 64 + ni * 16 + lr) * 64 + co];
            for (int mi = 0; mi < 4; ++mi)
                for (int ni = 0; ni < 4; ++ni)
                    acc[mi][ni] = __builtin_amdgcn_mfma_f32_16x16x32_f16(af[mi], bfr[ni], acc[mi][ni], 0, 0, 0);
        }
        __syncthreads();
    }

    // epilogue: bias, per-(row,head) l2 norm across d = ni*16+lr
    int h = (n0 >> 6) + wc;
    float bv[4];
    for (int ni = 0; ni < 4; ++ni) bv[ni] = bias[z * 1024 + n0 + wc * 64 + ni * 16 + lr];
    for (int mi = 0; mi < 4; ++mi)
        for (int ni = 0; ni < 4; ++ni)
            for (int r = 0; r < 4; ++r) acc[mi][ni][r] += bv[ni];

    float lsfac = __expf(fminf(lsc[h], LOGMAX)) * LOG2E;

    for (int mi = 0; mi < 4; ++mi)
        for (int r = 0; r < 4; ++r) {
            int row = m0 + wr * 64 + mi * 16 + lq * 4 + r;   // m = n*4 + b
            int n = row >> 2, b = row & 3;
            int bh = b * 16 + h;
            if (z < 2) {
                float ss = 0.f;
                for (int ni = 0; ni < 4; ++ni) ss += acc[mi][ni][r] * acc[mi][ni][r];
                for (int off = 1; off < 16; off <<= 1) ss += __shfl_xor(ss, off);
                float scale = 1.0f / fmaxf(sqrtf(ss), 1e-12f);
                if (z == 0) scale *= lsfac;
                unsigned short* dst = (z == 0) ? qn : kn;
                for (int ni = 0; ni < 4; ++ni)
                    dst[(size_t)bh * 65536 + (size_t)n * 64 + ni * 16 + lr] = f2h(acc[mi][ni][r] * scale);
            } else {
                for (int ni = 0; ni < 4; ++ni)
                    vT[(size_t)bh * 65536 + (size_t)(ni * 16 + lr) * 1024 + n] = f2h(acc[mi][ni][r]);
            }
        }
}

// ---- flash attention, static-max softmax, S^T orientation ----
// 1D grid of 1024; XCD swizzle: each XCD owns 8 heads x all q-tiles,
// qt fastest (head's K/V 256 KB stays L2-hot across the 16 q-tiles).
__global__ __launch_bounds__(256) void flash_kernel(
    const unsigned short* __restrict__ qn, const unsigned short* __restrict__ kn,
    const unsigned short* __restrict__ vT, const float* __restrict__ lsc,
    unsigned short* __restrict__ xb)
{
    __shared__ __align__(16) unsigned short K_flat[64 * 64];
    __shared__ __align__(16) unsigned short V_flat[64 * 64];  // [d][kpos]
    __shared__ __align__(16) unsigned short P_lds[4][16][72]; // [wave][qrow][kpos]
    int tid = threadIdx.x;
    int lane = tid & 63, wave = tid >> 6;
    int lr = lane & 15, lq = lane >> 4;

    int lin = blockIdx.x;
    int xcd = lin & 7, s = lin >> 3;
    int qt = s & 15, bh = xcd * 8 + (s >> 4);
    int q0 = qt * 64 + wave * 16;

    float off = __expf(fminf(lsc[bh & 15], LOGMAX)) * LOG2E - 12.0f;

    f16x8 qf[2];   // B-frag: Q[qrow=lr][d]
    for (int kc = 0; kc < 2; ++kc)
        qf[kc] = *(const f16x8*)(qn + (size_t)bh * 65536 + (size_t)(q0 + lr) * 64 + kc * 32 + lq * 8);

    int rl = lane >> 3;
    int cg = ((lane & 7) ^ rl) << 3;
    const unsigned short* gK = kn + (size_t)bh * 65536 + (size_t)(wave * 16 + rl) * 64 + cg;
    const unsigned short* gV = vT + (size_t)bh * 65536 + (size_t)(wave * 16 + rl) * 1024 + cg;
    unsigned short* lK = &K_flat[wave * 16 * 64];
    unsigned short* lV = &V_flat[wave * 16 * 64];
    int swz = lr & 7;
    int c0 = (lq ^ swz) << 3;
    int c1 = ((lq ^ 4) ^ swz) << 3;

    f32x4 o[4];    // O^T[d = nt*16 + lq*4 + r][qrow = lr]
    for (int i = 0; i < 4; i++) o[i] = (f32x4){0.f, 0.f, 0.f, 0.f};
    float lsum = 0.f;

    for (int kt = 0; kt < 16; ++kt) {
        for (int j = 0; j < 2; ++j) {
            GLOAD16(gK + kt * 4096 + j * 512,  lK + j * 512);
            GLOAD16(gV + kt * 64  + j * 8192,  lV + j * 512);
        }
        __syncthreads();

        // S^T[kpos][qrow]: A = K rows (m=kpos), B = Q rows (n=qrow)
        f32x4 sa[4];
        for (int ct = 0; ct < 4; ++ct) {
            f32x4 a = (f32x4){0.f, 0.f, 0.f, 0.f};
            for (int kc = 0; kc < 2; ++kc) {
                f16x8 kf = *(const f16x8*)&K_flat[(ct * 16 + lr) * 64 + (kc ? c1 : c0)];
                a = __builtin_amdgcn_mfma_f32_16x16x32_f16(kf, qf[kc], a, 0, 0, 0);
            }
            sa[ct] = a;   // lane: qrow=lr, kpos = ct*16 + lq*4 + r
        }

        for (int ct = 0; ct < 4; ++ct) {
            float p0 = exp2f(sa[ct][0] - off), p1 = exp2f(sa[ct][1] - off);
            float p2 = exp2f(sa[ct][2] - off), p3 = exp2f(sa[ct][3] - off);
            lsum += (p0 + p1) + (p2 + p3);
            ushort4 pw;
            pw.x = f2h(p0); pw.y = f2h(p1); pw.z = f2h(p2); pw.w = f2h(p3);
            *(ushort4*)&P_lds[wave][lr][ct * 16 + lq * 4] = pw;  // wave-private
        }

        // O^T += V^T @ P^T
        f16x8 pf[2];
        for (int kc = 0; kc < 2; ++kc)
            pf[kc] = *(const f16x8*)&P_lds[wave][lr][kc * 32 + lq * 8];
        for (int nt = 0; nt < 4; ++nt)
            for (int kc = 0; kc < 2; ++kc) {
                f16x8 vf = *(const f16x8*)&V_flat[(nt * 16 + lr) * 64 + (kc ? c1 : c0)];
                o[nt] = __builtin_amdgcn_mfma_f32_16x16x32_f16(vf, pf[kc], o[nt], 0, 0, 0);
            }
        __syncthreads();
    }

    lsum += __shfl_xor(lsum, 16);
    lsum += __shfl_xor(lsum, 32);
    float inv = 1.0f / lsum;

    // write xb row-major (m = n*4+b, c = h*64+d) so out_gemm stages contiguously
    int b = bh >> 4, h = bh & 15;
    for (int nt = 0; nt < 4; ++nt) {
        ushort4 w;
        w.x = f2h(o[nt][0] * inv); w.y = f2h(o[nt][1] * inv);
        w.z = f2h(o[nt][2] * inv); w.w = f2h(o[nt][3] * inv);
        size_t m = (size_t)(q0 + lr) * 4 + b;
        *(ushort4*)(xb + m * 1024 + h * 64 + nt * 16 + lq * 4) = w;
    }
}

// ---- output GEMM: out(4096x1024) = X @ out_w^T + out_b;  128x64 tiles ----
// 1D grid of 512; XCD swizzle: each XCD owns 4 m-tiles x all 16 n-tiles.
__global__ __launch_bounds__(256) void out_gemm(
    const unsigned short* __restrict__ xb, const unsigned short* __restrict__ owbf,
    const float* __restrict__ bias, float* __restrict__ outp)
{
    __shared__ __align__(16) unsigned short AsmF[128 * 64];
    __shared__ __align__(16) unsigned short BsmF[64 * 64];
    int tid = threadIdx.x;
    int lane = tid & 63, wave = tid >> 6;
    int lr = lane & 15, lq = lane >> 4;

    int lin = blockIdx.x;
    int xcd = lin & 7, s = lin >> 3;
    int xt = s & 15, yy = s >> 4;            // yy 0..3
    int m0 = (xcd * 4 + yy) * 128, n0 = xt * 64;

    int rl = lane >> 3;
    int cg = ((lane & 7) ^ rl) << 3;
    const unsigned short* gA = xb   + (size_t)(m0 + wave * 32 + rl) * 1024 + cg;
    const unsigned short* gB = owbf + (size_t)(n0 + wave * 16 + rl) * 1024 + cg;
    unsigned short* lA = &AsmF[wave * 32 * 64];
    unsigned short* lB = &BsmF[wave * 16 * 64];
    int swz = lr & 7;
    int c0 = (lq ^ swz) << 3;
    int c1 = ((lq ^ 4) ^ swz) << 3;

    f32x4 acc[2][4];
    for (int i = 0; i < 2; i++) for (int j = 0; j < 4; j++) acc[i][j] = (f32x4){0.f, 0.f, 0.f, 0.f};

    for (int ki = 0; ki < 16; ++ki) {
        for (int j = 0; j < 4; ++j)
            GLOAD16(gA + ki * 64 + j * 8192, lA + j * 512);
        for (int j = 0; j < 2; ++j)
            GLOAD16(gB + ki * 64 + j * 8192, lB + j * 512);
        __syncthreads();
        for (int kc = 0; kc < 2; ++kc) {
            int co = kc ? c1 : c0;
            f16x8 af[2], bfr[4];
            for (int mi = 0; mi < 2; ++mi) af[mi]  = *(const f16x8*)&AsmF[(wave * 32 + mi * 16 + lr) * 64 + co];
            for (int ni = 0; ni < 4; ++ni) bfr[ni] = *(const f16x8*)&BsmF[(ni * 16 + lr) * 64 + co];
            for (int mi = 0; mi < 2; ++mi)
                for (int ni = 0; ni < 4; ++ni)
                    acc[mi][ni] = __builtin_amdgcn_mfma_f32_16x16x32_f16(af[mi], bfr[ni], acc[mi][ni], 0, 0, 0);
        }
        __syncthreads();
    }
    for (int mi = 0; mi < 2; ++mi)
        for (int ni = 0; ni < 4; ++ni)
            for (int r = 0; r < 4; ++r) {
                int row = m0 + wave * 32 + mi * 16 + lq * 4 + r;
                int col = n0 + ni * 16 + lr;
                outp[(size_t)row * 1024 + col] = acc[mi][ni][r] + bias[col];
            }
}

extern "C" void kernel_launch(void* const* d_in, const int* in_sizes, int n_in,
                              void* d_out, int out_size, void* d_ws, size_t ws_size,
                              hipStream_t stream) {
    const float* query = (const float*)d_in[0];
    const float* key   = (const float*)d_in[1];
    const float* value = (const float*)d_in[2];
    const float* ipw   = (const float*)d_in[3];
    const float* ipb   = (const float*)d_in[4];
    const float* lsc   = (const float*)d_in[5];
    const float* ow    = (const float*)d_in[6];
    const float* ob    = (const float*)d_in[7];
    float* outp = (float*)d_out;

    char* ws = (char*)d_ws;
    unsigned short* qbf  = (unsigned short*)(ws);               // 8 MB fp16 query
    unsigned short* kbf  = (unsigned short*)(ws + 8388608);     // 8 MB
    unsigned short* vbf  = (unsigned short*)(ws + 16777216);    // 8 MB
    unsigned short* wbf  = (unsigned short*)(ws + 25165824);    // 6 MB in_proj_w
    unsigned short* owbf = (unsigned short*)(ws + 31457280);    // 2 MB out_w
    unsigned short* qn   = (unsigned short*)(ws + 33554432);    // 8 MB normalized q (bh,n,d)
    unsigned short* kn   = (unsigned short*)(ws + 41943040);    // 8 MB normalized k
    unsigned short* vT   = (unsigned short*)(ws + 50331648);    // 8 MB v^T (bh,d,n)
    unsigned short* xbuf = (unsigned short*)(ws + 58720256);    // 8 MB attn out (m, c) row-major

    cvt_all<<<16384, 256, 0, stream>>>(query, key, value, ipw, ow,
                                       qbf, kbf, vbf, wbf, owbf);
    proj_gemm<<<768, 256, 0, stream>>>(qbf, kbf, vbf, wbf, ipb, lsc, qn, kn, vT);
    flash_kernel<<<1024, 256, 0, stream>>>(qn, kn, vT, lsc, xbuf);
    out_gemm<<<512, 256, 0, stream>>>(xbuf, owbf, ob, outp);
}

// Round 6
// 207.236 us; speedup vs baseline: 1.4272x; 1.0245x over previous
//
#include <hip/hip_runtime.h>

// ---------------------------------------------------------------------------
// CustomAttention: cosine-sim MHA.  N=1024 seq, B=4 batch, C=1024, H=16, hd=64
// R6: flash is LDS-read-throughput bound (per-SIMD MFMA ~5k cyc vs ~55k cyc of
//     ds_read_b128 per CU).  New flash: 128 q-rows/block, 2 q-groups per wave
//     -> K/V frag reads shared across both groups (LDS ops/FLOP ~halved),
//     barriers per work halved; QK acc initialized to -off (softmax offset
//     folded into the MFMA C operand).  proj/out/cvt unchanged from R5.
// ---------------------------------------------------------------------------

typedef _Float16 f16x8 __attribute__((ext_vector_type(8)));
typedef float    f32x4 __attribute__((ext_vector_type(4)));

#define LOG2E 1.4426950408889634f
#define LOGMAX 4.6051702f   // log(100)

#define GLOAD16(g, l) \
    __builtin_amdgcn_global_load_lds((__attribute__((address_space(1))) void*)(g), \
                                     (__attribute__((address_space(3))) void*)(l), 16, 0, 0)

__device__ __forceinline__ unsigned short f2h(float x) {
    union { _Float16 h; unsigned short u; } cv;
    cv.h = (_Float16)x;
    return cv.u;
}

// ---- fp32 -> fp16 convert, all 5 tensors in one launch ----
__global__ __launch_bounds__(256) void cvt_all(
    const float* __restrict__ q, const float* __restrict__ k,
    const float* __restrict__ v, const float* __restrict__ w,
    const float* __restrict__ ow,
    unsigned short* __restrict__ qbf, unsigned short* __restrict__ kbf,
    unsigned short* __restrict__ vbf, unsigned short* __restrict__ wbf,
    unsigned short* __restrict__ owbf)
{
    int b = blockIdx.x;
    const float* src; unsigned short* dst; int idx;
    if      (b < 4096)  { src = q;  dst = qbf;  idx = b; }
    else if (b < 8192)  { src = k;  dst = kbf;  idx = b - 4096; }
    else if (b < 12288) { src = v;  dst = vbf;  idx = b - 8192; }
    else if (b < 15360) { src = w;  dst = wbf;  idx = b - 12288; }
    else                { src = ow; dst = owbf; idx = b - 15360; }
    int i = idx * 256 + threadIdx.x;
    float4 val = ((const float4*)src)[i];
    ushort4 o;
    o.x = f2h(val.x); o.y = f2h(val.y); o.z = f2h(val.z); o.w = f2h(val.w);
    ((ushort4*)dst)[i] = o;
}

// ---- projection GEMM + fused l2norm epilogue (unchanged from R5) ----
__global__ __launch_bounds__(256) void proj_gemm(
    const unsigned short* __restrict__ qbf, const unsigned short* __restrict__ kbf,
    const unsigned short* __restrict__ vbf, const unsigned short* __restrict__ wbf,
    const float* __restrict__ bias, const float* __restrict__ lsc,
    unsigned short* __restrict__ qn, unsigned short* __restrict__ kn,
    unsigned short* __restrict__ vT)
{
    __shared__ __align__(16) unsigned short AsmF[128 * 64];
    __shared__ __align__(16) unsigned short BsmF[128 * 64];
    int tid = threadIdx.x;
    int lane = tid & 63, wave = tid >> 6;
    int lr = lane & 15, lq = lane >> 4;
    int wr = wave >> 1, wc = wave & 1;

    int lin = blockIdx.x;
    int xcd = lin & 7, s = lin >> 3;
    int xt = s & 7, yy = (s >> 3) & 3, z = s >> 5;
    int m0 = (xcd * 4 + yy) * 128, n0 = xt * 128;

    const unsigned short* A = (z == 0) ? qbf : (z == 1) ? kbf : vbf;
    const unsigned short* W = wbf + (size_t)z * 1024 * 1024;

    int rl = lane >> 3;
    int cg = ((lane & 7) ^ rl) << 3;                     // halves
    const unsigned short* gA = A + (size_t)(m0 + wave * 32 + rl) * 1024 + cg;
    const unsigned short* gB = W + (size_t)(n0 + wave * 32 + rl) * 1024 + cg;
    unsigned short* lA = &AsmF[wave * 32 * 64];
    unsigned short* lB = &BsmF[wave * 32 * 64];

    int swz = lr & 7;
    int c0 = (lq ^ swz) << 3;
    int c1 = ((lq ^ 4) ^ swz) << 3;

    f32x4 acc[4][4];
    for (int i = 0; i < 4; i++) for (int j = 0; j < 4; j++) acc[i][j] = (f32x4){0.f, 0.f, 0.f, 0.f};

    for (int ki = 0; ki < 16; ++ki) {
        for (int j = 0; j < 4; ++j) {
            GLOAD16(gA + ki * 64 + j * 8192, lA + j * 512);
            GLOAD16(gB + ki * 64 + j * 8192, lB + j * 512);
        }
        __syncthreads();
        for (int kc = 0; kc < 2; ++kc) {
            int co = kc ? c1 : c0;
            f16x8 af[4], bfr[4];
            for (int mi = 0; mi < 4; ++mi) af[mi]  = *(const f16x8*)&AsmF[(wr * 64 + mi * 16 + lr) * 64 + co];
            for (int ni = 0; ni < 4; ++ni) bfr[ni] = *(const f16x8*)&BsmF[(wc * 64 + ni * 16 + lr) * 64 + co];
            for (int mi = 0; mi < 4; ++mi)
                for (int ni = 0; ni < 4; ++ni)
                    acc[mi][ni] = __builtin_amdgcn_mfma_f32_16x16x32_f16(af[mi], bfr[ni], acc[mi][ni], 0, 0, 0);
        }
        __syncthreads();
    }

    int h = (n0 >> 6) + wc;
    float bv[4];
    for (int ni = 0; ni < 4; ++ni) bv[ni] = bias[z * 1024 + n0 + wc * 64 + ni * 16 + lr];
    for (int mi = 0; mi < 4; ++mi)
        for (int ni = 0; ni < 4; ++ni)
            for (int r = 0; r < 4; ++r) acc[mi][ni][r] += bv[ni];

    float lsfac = __expf(fminf(lsc[h], LOGMAX)) * LOG2E;

    for (int mi = 0; mi < 4; ++mi)
        for (int r = 0; r < 4; ++r) {
            int row = m0 + wr * 64 + mi * 16 + lq * 4 + r;   // m = n*4 + b
            int n = row >> 2, b = row & 3;
            int bh = b * 16 + h;
            if (z < 2) {
                float ss = 0.f;
                for (int ni = 0; ni < 4; ++ni) ss += acc[mi][ni][r] * acc[mi][ni][r];
                for (int off = 1; off < 16; off <<= 1) ss += __shfl_xor(ss, off);
                float scale = 1.0f / fmaxf(sqrtf(ss), 1e-12f);
                if (z == 0) scale *= lsfac;
                unsigned short* dst = (z == 0) ? qn : kn;
                for (int ni = 0; ni < 4; ++ni)
                    dst[(size_t)bh * 65536 + (size_t)n * 64 + ni * 16 + lr] = f2h(acc[mi][ni][r] * scale);
            } else {
                for (int ni = 0; ni < 4; ++ni)
                    vT[(size_t)bh * 65536 + (size_t)(ni * 16 + lr) * 1024 + n] = f2h(acc[mi][ni][r]);
            }
        }
}

// ---- flash attention: 128 q-rows/block, 2 q-groups per wave ----
// grid 512; XCD swizzle: xcd owns 8 heads x 8 q-tiles, qt fastest.
// Wave w, group g covers q-rows q0 + g*64 + w*16 + lr.  K/V frag reads are
// shared across both groups (the LDS-pipe fix).  QK acc init = -off.
__global__ __launch_bounds__(256) void flash_kernel(
    const unsigned short* __restrict__ qn, const unsigned short* __restrict__ kn,
    const unsigned short* __restrict__ vT, const float* __restrict__ lsc,
    unsigned short* __restrict__ xb)
{
    __shared__ __align__(16) unsigned short K_flat[64 * 64];
    __shared__ __align__(16) unsigned short V_flat[64 * 64];     // [d][kpos]
    __shared__ __align__(16) unsigned short P_lds[4][2][16][72]; // [wave][grp][qrow][kpos]
    int tid = threadIdx.x;
    int lane = tid & 63, wave = tid >> 6;
    int lr = lane & 15, lq = lane >> 4;

    int lin = blockIdx.x;
    int xcd = lin & 7, s = lin >> 3;
    int qt = s & 7, bh = xcd * 8 + (s >> 3);
    int q0 = qt * 128;

    // static softmax offset folded into QK accumulator init
    float off = __expf(fminf(lsc[bh & 15], LOGMAX)) * LOG2E - 12.0f;
    f32x4 initv = (f32x4){-off, -off, -off, -off};

    f16x8 qf[2][2];   // [group][kc]  B-frag: Q[qrow][d]
    for (int g = 0; g < 2; ++g)
        for (int kc = 0; kc < 2; ++kc)
            qf[g][kc] = *(const f16x8*)(qn + (size_t)bh * 65536 +
                          (size_t)(q0 + g * 64 + wave * 16 + lr) * 64 + kc * 32 + lq * 8);

    int rl = lane >> 3;
    int cg = ((lane & 7) ^ rl) << 3;
    const unsigned short* gK = kn + (size_t)bh * 65536 + (size_t)(wave * 16 + rl) * 64 + cg;
    const unsigned short* gV = vT + (size_t)bh * 65536 + (size_t)(wave * 16 + rl) * 1024 + cg;
    unsigned short* lK = &K_flat[wave * 16 * 64];
    unsigned short* lV = &V_flat[wave * 16 * 64];
    int swz = lr & 7;
    int c0 = (lq ^ swz) << 3;
    int c1 = ((lq ^ 4) ^ swz) << 3;

    f32x4 o[2][4];    // [group][nt]  O^T[d][qrow]
    for (int g = 0; g < 2; ++g) for (int i = 0; i < 4; i++) o[g][i] = (f32x4){0.f, 0.f, 0.f, 0.f};
    float lsum[2] = {0.f, 0.f};

    for (int kt = 0; kt < 16; ++kt) {
        for (int j = 0; j < 2; ++j) {
            GLOAD16(gK + kt * 4096 + j * 512,  lK + j * 512);
            GLOAD16(gV + kt * 64  + j * 8192,  lV + j * 512);
        }
        __syncthreads();

        // S^T = K Q^T - off : one K-frag read feeds both q-groups
        f32x4 sc[2][4];
        for (int ct = 0; ct < 4; ++ct) {
            for (int kc = 0; kc < 2; ++kc) {
                f16x8 kf = *(const f16x8*)&K_flat[(ct * 16 + lr) * 64 + (kc ? c1 : c0)];
                for (int g = 0; g < 2; ++g)
                    sc[g][ct] = __builtin_amdgcn_mfma_f32_16x16x32_f16(
                        kf, qf[g][kc], kc == 0 ? initv : sc[g][ct], 0, 0, 0);
            }
        }

        // p = exp2(sc); per-lane l accumulate; pack to wave/group-private LDS
        for (int g = 0; g < 2; ++g)
            for (int ct = 0; ct < 4; ++ct) {
                float p0 = exp2f(sc[g][ct][0]), p1 = exp2f(sc[g][ct][1]);
                float p2 = exp2f(sc[g][ct][2]), p3 = exp2f(sc[g][ct][3]);
                lsum[g] += (p0 + p1) + (p2 + p3);
                ushort4 pw;
                pw.x = f2h(p0); pw.y = f2h(p1); pw.z = f2h(p2); pw.w = f2h(p3);
                *(ushort4*)&P_lds[wave][g][lr][ct * 16 + lq * 4] = pw;
            }

        // O^T += V^T @ P^T : one V-frag read feeds both groups
        f16x8 pf[2][2];
        for (int g = 0; g < 2; ++g)
            for (int kc = 0; kc < 2; ++kc)
                pf[g][kc] = *(const f16x8*)&P_lds[wave][g][lr][kc * 32 + lq * 8];
        for (int nt = 0; nt < 4; ++nt)
            for (int kc = 0; kc < 2; ++kc) {
                f16x8 vf = *(const f16x8*)&V_flat[(nt * 16 + lr) * 64 + (kc ? c1 : c0)];
                for (int g = 0; g < 2; ++g)
                    o[g][nt] = __builtin_amdgcn_mfma_f32_16x16x32_f16(vf, pf[g][kc], o[g][nt], 0, 0, 0);
            }
        __syncthreads();
    }

    int b = bh >> 4, h = bh & 15;
    for (int g = 0; g < 2; ++g) {
        float ls = lsum[g];
        ls += __shfl_xor(ls, 16);
        ls += __shfl_xor(ls, 32);
        float inv = 1.0f / ls;
        size_t m = (size_t)(q0 + g * 64 + wave * 16 + lr) * 4 + b;
        for (int nt = 0; nt < 4; ++nt) {
            ushort4 w;
            w.x = f2h(o[g][nt][0] * inv); w.y = f2h(o[g][nt][1] * inv);
            w.z = f2h(o[g][nt][2] * inv); w.w = f2h(o[g][nt][3] * inv);
            *(ushort4*)(xb + m * 1024 + h * 64 + nt * 16 + lq * 4) = w;
        }
    }
}

// ---- output GEMM: out(4096x1024) = X @ out_w^T + out_b;  128x64 tiles ----
__global__ __launch_bounds__(256) void out_gemm(
    const unsigned short* __restrict__ xb, const unsigned short* __restrict__ owbf,
    const float* __restrict__ bias, float* __restrict__ outp)
{
    __shared__ __align__(16) unsigned short AsmF[128 * 64];
    __shared__ __align__(16) unsigned short BsmF[64 * 64];
    int tid = threadIdx.x;
    int lane = tid & 63, wave = tid >> 6;
    int lr = lane & 15, lq = lane >> 4;

    int lin = blockIdx.x;
    int xcd = lin & 7, s = lin >> 3;
    int xt = s & 15, yy = s >> 4;
    int m0 = (xcd * 4 + yy) * 128, n0 = xt * 64;

    int rl = lane >> 3;
    int cg = ((lane & 7) ^ rl) << 3;
    const unsigned short* gA = xb   + (size_t)(m0 + wave * 32 + rl) * 1024 + cg;
    const unsigned short* gB = owbf + (size_t)(n0 + wave * 16 + rl) * 1024 + cg;
    unsigned short* lA = &AsmF[wave * 32 * 64];
    unsigned short* lB = &BsmF[wave * 16 * 64];
    int swz = lr & 7;
    int c0 = (lq ^ swz) << 3;
    int c1 = ((lq ^ 4) ^ swz) << 3;

    f32x4 acc[2][4];
    for (int i = 0; i < 2; i++) for (int j = 0; j < 4; j++) acc[i][j] = (f32x4){0.f, 0.f, 0.f, 0.f};

    for (int ki = 0; ki < 16; ++ki) {
        for (int j = 0; j < 4; ++j)
            GLOAD16(gA + ki * 64 + j * 8192, lA + j * 512);
        for (int j = 0; j < 2; ++j)
            GLOAD16(gB + ki * 64 + j * 8192, lB + j * 512);
        __syncthreads();
        for (int kc = 0; kc < 2; ++kc) {
            int co = kc ? c1 : c0;
            f16x8 af[2], bfr[4];
            for (int mi = 0; mi < 2; ++mi) af[mi]  = *(const f16x8*)&AsmF[(wave * 32 + mi * 16 + lr) * 64 + co];
            for (int ni = 0; ni < 4; ++ni) bfr[ni] = *(const f16x8*)&BsmF[(ni * 16 + lr) * 64 + co];
            for (int mi = 0; mi < 2; ++mi)
                for (int ni = 0; ni < 4; ++ni)
                    acc[mi][ni] = __builtin_amdgcn_mfma_f32_16x16x32_f16(af[mi], bfr[ni], acc[mi][ni], 0, 0, 0);
        }
        __syncthreads();
    }
    for (int mi = 0; mi < 2; ++mi)
        for (int ni = 0; ni < 4; ++ni)
            for (int r = 0; r < 4; ++r) {
                int row = m0 + wave * 32 + mi * 16 + lq * 4 + r;
                int col = n0 + ni * 16 + lr;
                outp[(size_t)row * 1024 + col] = acc[mi][ni][r] + bias[col];
            }
}

extern "C" void kernel_launch(void* const* d_in, const int* in_sizes, int n_in,
                              void* d_out, int out_size, void* d_ws, size_t ws_size,
                              hipStream_t stream) {
    const float* query = (const float*)d_in[0];
    const float* key   = (const float*)d_in[1];
    const float* value = (const float*)d_in[2];
    const float* ipw   = (const float*)d_in[3];
    const float* ipb   = (const float*)d_in[4];
    const float* lsc   = (const float*)d_in[5];
    const float* ow    = (const float*)d_in[6];
    const float* ob    = (const float*)d_in[7];
    float* outp = (float*)d_out;

    char* ws = (char*)d_ws;
    unsigned short* qbf  = (unsigned short*)(ws);               // 8 MB fp16 query
    unsigned short* kbf  = (unsigned short*)(ws + 8388608);     // 8 MB
    unsigned short* vbf  = (unsigned short*)(ws + 16777216);    // 8 MB
    unsigned short* wbf  = (unsigned short*)(ws + 25165824);    // 6 MB in_proj_w
    unsigned short* owbf = (unsigned short*)(ws + 31457280);    // 2 MB out_w
    unsigned short* qn   = (unsigned short*)(ws + 33554432);    // 8 MB normalized q (bh,n,d)
    unsigned short* kn   = (unsigned short*)(ws + 41943040);    // 8 MB normalized k
    unsigned short* vT   = (unsigned short*)(ws + 50331648);    // 8 MB v^T (bh,d,n)
    unsigned short* xbuf = (unsigned short*)(ws + 58720256);    // 8 MB attn out (m, c) row-major

    cvt_all<<<16384, 256, 0, stream>>>(query, key, value, ipw, ow,
                                       qbf, kbf, vbf, wbf, owbf);
    proj_gemm<<<768, 256, 0, stream>>>(qbf, kbf, vbf, wbf, ipb, lsc, qn, kn, vT);
    flash_kernel<<<512, 256, 0, stream>>>(qn, kn, vT, lsc, xbuf);
    out_gemm<<<512, 256, 0, stream>>>(xbuf, owbf, ob, outp);
}